// Round 1
// baseline (847.785 us; speedup 1.0000x reference)
//
#include <hip/hip_runtime.h>
#include <math.h>

#define NB 4
#define LL 16384
#define HH 8
#define DD 64
#define NHH 32            // NB*HH
#define EPSF 1e-6f
#define SPLIT 32          // s-chunks per (n,h) in phase 1
#define SCHUNK (LL / SPLIT)   // 512

__device__ __forceinline__ float feat(float x) {
    // elu(x) + 1
    return x > 0.0f ? x + 1.0f : expf(x);
}

__global__ void zero_kernel(float* __restrict__ p, int n) {
    int i = blockIdx.x * 256 + threadIdx.x;
    if (i < n) p[i] = 0.0f;
}

// Phase 1: kv[nh][m][d] = sum_s feat(k[s][d]) * v[s][m];  ksum[nh][d] = sum_s feat(k[s][d])
// grid = NHH*SPLIT blocks of 256 threads. Each wave holds a full 64x64 partial (8x8 per lane)
// over its s-subset; cross-wave reduce in swizzled LDS; commit to per-block partials (or atomics).
__global__ __launch_bounds__(256, 4) void phase1_kernel(
        const float* __restrict__ kg, const float* __restrict__ vg,
        float* __restrict__ kvf, float* __restrict__ ksf,
        float* __restrict__ part, int use_part) {
    __shared__ float smem[4160];   // staging: 16x64 (k) + 16x64 (v) = 2048; reduce: 64*65 = 4160

    int b = blockIdx.x;
    int nh = b >> 5;
    int chunk = b & 31;
    int n = nh >> 3, h = nh & 7;
    int s0base = chunk * SCHUNK;

    int tid  = threadIdx.x;
    int wave = tid >> 6;
    int lane = tid & 63;
    int dg = lane & 7;        // d-group
    int mg = lane >> 3;       // m-group
    int d0 = dg << 3;
    int m0 = mg << 3;

    float acc[8][8];
    #pragma unroll
    for (int a = 0; a < 8; ++a)
        #pragma unroll
        for (int c = 0; c < 8; ++c) acc[a][c] = 0.0f;
    float ks[8];
    #pragma unroll
    for (int a = 0; a < 8; ++a) ks[a] = 0.0f;

    const float* kb = kg + ((size_t)n * LL * HH + h) * DD;
    const float* vb = vg + ((size_t)n * LL * HH + h) * DD;

    for (int r = 0; r < SCHUNK / 16; ++r) {
        int s0 = s0base + (r << 4);
        __syncthreads();
        // stage 16 rows of k (featured) and 16 rows of v: 2048 floats, 8 scalars/thread,
        // coalesced global reads, conflict-free LDS writes (identity mapping).
        #pragma unroll
        for (int i = 0; i < 8; ++i) {
            int e = tid + (i << 8);          // 0..2047
            int rw = (e >> 6) & 15;
            int col = e & 63;
            float x;
            if (i < 4) x = feat(kb[(size_t)(s0 + rw) * (HH * DD) + col]);
            else       x = vb[(size_t)(s0 + rw) * (HH * DD) + col];
            smem[e] = x;
        }
        __syncthreads();
        // each wave processes its own 4 staged rows
        #pragma unroll
        for (int j = 0; j < 4; ++j) {
            int sl = (wave << 2) + j;
            float4 fka = *(float4*)&smem[sl * 64 + d0];
            float4 fkb = *(float4*)&smem[sl * 64 + d0 + 4];
            float4 fva = *(float4*)&smem[1024 + sl * 64 + m0];
            float4 fvb = *(float4*)&smem[1024 + sl * 64 + m0 + 4];
            float fk[8] = {fka.x, fka.y, fka.z, fka.w, fkb.x, fkb.y, fkb.z, fkb.w};
            float fv[8] = {fva.x, fva.y, fva.z, fva.w, fvb.x, fvb.y, fvb.z, fvb.w};
            #pragma unroll
            for (int di = 0; di < 8; ++di)
                #pragma unroll
                for (int mi = 0; mi < 8; ++mi)
                    acc[di][mi] = fmaf(fk[di], fv[mi], acc[di][mi]);
            if (mg == 0) {
                #pragma unroll
                for (int di = 0; di < 8; ++di) ks[di] += fk[di];
            }
        }
    }

    // cross-wave reduction in LDS with bank-spreading swizzle: addr(m,d) = m*65 + (d ^ (m>>3))
    for (int w = 0; w < 4; ++w) {
        __syncthreads();
        if (wave == w) {
            #pragma unroll
            for (int di = 0; di < 8; ++di)
                #pragma unroll
                for (int mi = 0; mi < 8; ++mi) {
                    int m = m0 + mi;
                    int d = d0 + di;
                    int a = m * 65 + (d ^ mg);
                    if (w == 0) smem[a] = acc[di][mi];
                    else        smem[a] += acc[di][mi];
                }
        }
    }
    __syncthreads();

    // commit 4096 floats
    if (use_part) {
        float* pb = part + (size_t)b * 4096;
        #pragma unroll
        for (int i = 0; i < 16; ++i) {
            int e = tid + (i << 8);
            int m = e >> 6, d = e & 63;
            pb[e] = smem[m * 65 + (d ^ ((m >> 3) & 7))];
        }
    } else {
        float* kvb = kvf + (size_t)nh * 4096;
        #pragma unroll
        for (int i = 0; i < 16; ++i) {
            int e = tid + (i << 8);
            int m = e >> 6, d = e & 63;
            atomicAdd(&kvb[e], smem[m * 65 + (d ^ ((m >> 3) & 7))]);
        }
    }
    // ksum: small atomic commit (lanes with mg==0 hold it)
    if (mg == 0) {
        #pragma unroll
        for (int di = 0; di < 8; ++di)
            atomicAdd(&ksf[nh * 64 + d0 + di], ks[di]);
    }
}

// sum 32 per-chunk partials -> final kv
__global__ void reduce_kernel(const float* __restrict__ part, float* __restrict__ kvf) {
    int eg = blockIdx.x * 256 + threadIdx.x;    // < 131072
    int nh = eg >> 12;
    int e = eg & 4095;
    const float* p = part + ((size_t)nh << 17) + e;   // nh*32*4096
    float s = 0.0f;
    #pragma unroll
    for (int c = 0; c < 32; ++c)
        s += p[(size_t)c << 12];
    kvf[eg] = s;
}

// Phase 2: out[nh][l][m] = z(l) * sum_d feat(q[l][d]) * kv[m][d]
// grid = NHH * (LL/128) blocks, 256 threads, Ltile=128, 4l x 8m per-thread tile.
__global__ __launch_bounds__(256, 3) void phase2_kernel(
        const float* __restrict__ qg, const float* __restrict__ kvf,
        const float* __restrict__ ksf, float* __restrict__ out) {
    __shared__ float s_kv[64 * 68];
    __shared__ float s_qf[128 * 68];
    __shared__ float s_z[128];

    int b = blockIdx.x;
    int nh = b >> 7;               // /128 tiles
    int lt = (b & 127) << 7;       // tile base l
    int n = nh >> 3, h = nh & 7;
    int tid = threadIdx.x;

    // load kv[nh][m][d] into LDS (pitch 68)
    const float* kvg = kvf + (size_t)nh * 4096;
    #pragma unroll
    for (int kk = 0; kk < 4; ++kk) {
        int e4 = tid + (kk << 8);               // float4 index, 0..1023
        int m = e4 >> 4;
        int dcol = (e4 & 15) << 2;
        float4 x = *(const float4*)(kvg + ((size_t)e4 << 2));
        *(float4*)&s_kv[m * 68 + dcol] = x;
    }

    int dq = (tid & 15) << 2;
    float4 ks4 = *(const float4*)(ksf + nh * 64 + dq);

    // load q tile, apply feature map, compute z via 16-lane reduction
    const float* qb = qg + (((size_t)n * LL + lt) * HH + h) * DD;
    #pragma unroll
    for (int p = 0; p < 8; ++p) {
        int r = (p << 4) + (tid >> 4);
        float4 x = *(const float4*)(qb + (size_t)r * (HH * DD) + dq);
        float4 f;
        f.x = feat(x.x); f.y = feat(x.y); f.z = feat(x.z); f.w = feat(x.w);
        *(float4*)&s_qf[r * 68 + dq] = f;
        float pz = f.x * ks4.x + f.y * ks4.y + f.z * ks4.z + f.w * ks4.w;
        pz += __shfl_xor(pz, 1);
        pz += __shfl_xor(pz, 2);
        pz += __shfl_xor(pz, 4);
        pz += __shfl_xor(pz, 8);
        if ((tid & 15) == 0) s_z[r] = 1.0f / (pz + EPSF);
    }
    __syncthreads();

    int t = tid & 31;              // l-lane (strided l assignment: l = t + 32*i)
    int m0 = (tid >> 5) << 3;      // 8 m's per thread

    float acc[4][8];
    #pragma unroll
    for (int i2 = 0; i2 < 4; ++i2)
        #pragma unroll
        for (int j = 0; j < 8; ++j) acc[i2][j] = 0.0f;

    #pragma unroll
    for (int dB = 0; dB < 64; dB += 4) {
        float4 qv[4];
        #pragma unroll
        for (int i2 = 0; i2 < 4; ++i2)
            qv[i2] = *(float4*)&s_qf[(t + (i2 << 5)) * 68 + dB];
        #pragma unroll
        for (int j = 0; j < 8; ++j) {
            float4 kd = *(float4*)&s_kv[(m0 + j) * 68 + dB];
            #pragma unroll
            for (int i2 = 0; i2 < 4; ++i2) {
                acc[i2][j] = fmaf(qv[i2].x, kd.x, acc[i2][j]);
                acc[i2][j] = fmaf(qv[i2].y, kd.y, acc[i2][j]);
                acc[i2][j] = fmaf(qv[i2].z, kd.z, acc[i2][j]);
                acc[i2][j] = fmaf(qv[i2].w, kd.w, acc[i2][j]);
            }
        }
    }

    // epilogue: scale by z, store out[nh][l][m]
    float* ob = out + ((size_t)nh * LL + lt) * 64;
    #pragma unroll
    for (int i2 = 0; i2 < 4; ++i2) {
        int l = t + (i2 << 5);
        float z = s_z[l];
        float4 o0, o1;
        o0.x = acc[i2][0] * z; o0.y = acc[i2][1] * z;
        o0.z = acc[i2][2] * z; o0.w = acc[i2][3] * z;
        o1.x = acc[i2][4] * z; o1.y = acc[i2][5] * z;
        o1.z = acc[i2][6] * z; o1.w = acc[i2][7] * z;
        *(float4*)(ob + (size_t)l * 64 + m0) = o0;
        *(float4*)(ob + (size_t)l * 64 + m0 + 4) = o1;
    }
}

extern "C" void kernel_launch(void* const* d_in, const int* in_sizes, int n_in,
                              void* d_out, int out_size, void* d_ws, size_t ws_size,
                              hipStream_t stream) {
    const float* qg = (const float*)d_in[0];
    const float* kg = (const float*)d_in[1];
    const float* vg = (const float*)d_in[2];
    float* outp = (float*)d_out;

    float* kvf  = (float*)d_ws;                 // [32][64][64]
    float* ksf  = kvf + NHH * 4096;             // [32][64]
    float* part = ksf + NHH * 64;               // [1024][4096] (optional)

    size_t need = ((size_t)NHH * 4096 + NHH * 64 + (size_t)NHH * SPLIT * 4096) * sizeof(float);
    int use_part = (ws_size >= need) ? 1 : 0;

    hipLaunchKernelGGL(zero_kernel, dim3(520), dim3(256), 0, stream,
                       kvf, NHH * 4096 + NHH * 64);
    hipLaunchKernelGGL(phase1_kernel, dim3(NHH * SPLIT), dim3(256), 0, stream,
                       kg, vg, kvf, ksf, part, use_part);
    if (use_part)
        hipLaunchKernelGGL(reduce_kernel, dim3(512), dim3(256), 0, stream, part, kvf);
    hipLaunchKernelGGL(phase2_kernel, dim3(NHH * (LL / 128)), dim3(256), 0, stream,
                       qg, kvf, ksf, outp);
}

// Round 2
// 460.467 us; speedup vs baseline: 1.8411x; 1.8411x over previous
//
#include <hip/hip_runtime.h>
#include <math.h>

#define NB 4
#define LL 16384
#define HH 8
#define DD 64
#define NHH 32             // NB*HH
#define EPSF 1e-6f
#define SPLIT 32           // s-chunks per (n,h) in phase 1
#define SCHUNK (LL / SPLIT)    // 512
#define ROWS 32            // s-rows staged per round

__device__ __forceinline__ float feat(float x) {
    // elu(x) + 1
    return x > 0.0f ? x + 1.0f : expf(x);
}

// Phase 1: per-chunk partials of kv[m][d] = sum_s feat(k[s][d]) * v[s][m] and
// ksum[d] = sum_s feat(k[s][d]).  grid = NHH*SPLIT = 1024 blocks x 256 threads.
// Each wave holds a full 64x64 partial (8x8 per lane) over its 8-row slices;
// cross-wave reduce in swizzled LDS; NO atomics: partials go to d_out scratch.
__global__ __launch_bounds__(256, 2) void phase1_kernel(
        const float* __restrict__ kg, const float* __restrict__ vg,
        float* __restrict__ part, float* __restrict__ kspart) {
    __shared__ float smem[4160];   // staging: [0,2048) k, [2048,4096) v; reduce aliases [0,4160)

    int b = blockIdx.x;
    int nh = b >> 5;
    int chunk = b & 31;
    int n = nh >> 3, h = nh & 7;
    int s0base = chunk * SCHUNK;

    int tid  = threadIdx.x;
    int wave = tid >> 6;
    int lane = tid & 63;
    int dg = lane & 7;        // d-group
    int mg = lane >> 3;       // m-group
    int d0 = dg << 3;
    int m0 = mg << 3;

    float acc[8][8];
    #pragma unroll
    for (int a = 0; a < 8; ++a)
        #pragma unroll
        for (int c = 0; c < 8; ++c) acc[a][c] = 0.0f;
    float ks[8];
    #pragma unroll
    for (int a = 0; a < 8; ++a) ks[a] = 0.0f;

    const float* kb = kg + ((size_t)n * LL * HH + h) * DD;
    const float* vb = vg + ((size_t)n * LL * HH + h) * DD;

    int row = tid >> 4;             // 0..15 (loads rows row and row+16)
    int c4  = (tid & 15) << 2;      // column (float4)

    for (int r = 0; r < SCHUNK / ROWS; ++r) {     // 16 rounds
        int s0 = s0base + r * ROWS;
        __syncthreads();
        // stage 32 rows of k (featured) + v: 2 float4 loads per array per thread
        #pragma unroll
        for (int half = 0; half < 2; ++half) {
            int rw = row + (half << 4);
            const float* krow = kb + (size_t)(s0 + rw) * (HH * DD) + c4;
            const float* vrow = vb + (size_t)(s0 + rw) * (HH * DD) + c4;
            float4 xk = *(const float4*)krow;
            float4 xv = *(const float4*)vrow;
            xk.x = feat(xk.x); xk.y = feat(xk.y);
            xk.z = feat(xk.z); xk.w = feat(xk.w);
            *(float4*)&smem[rw * 64 + c4] = xk;
            *(float4*)&smem[2048 + rw * 64 + c4] = xv;
        }
        __syncthreads();
        // each wave processes its own 8 staged rows
        #pragma unroll
        for (int j = 0; j < 8; ++j) {
            int sl = (wave << 3) + j;
            float4 a0 = *(float4*)&smem[sl * 64 + d0];
            float4 a1 = *(float4*)&smem[sl * 64 + d0 + 4];
            float4 b0 = *(float4*)&smem[2048 + sl * 64 + m0];
            float4 b1 = *(float4*)&smem[2048 + sl * 64 + m0 + 4];
            float fk[8] = {a0.x, a0.y, a0.z, a0.w, a1.x, a1.y, a1.z, a1.w};
            float fv[8] = {b0.x, b0.y, b0.z, b0.w, b1.x, b1.y, b1.z, b1.w};
            #pragma unroll
            for (int di = 0; di < 8; ++di)
                #pragma unroll
                for (int mi = 0; mi < 8; ++mi)
                    acc[di][mi] = fmaf(fk[di], fv[mi], acc[di][mi]);
            if (mg == 0) {
                #pragma unroll
                for (int di = 0; di < 8; ++di) ks[di] += fk[di];
            }
        }
    }

    // cross-wave reduction in LDS, bank-spread swizzle addr(m,d) = m*65 + (d ^ mg)
    for (int w = 0; w < 4; ++w) {
        __syncthreads();
        if (wave == w) {
            #pragma unroll
            for (int di = 0; di < 8; ++di)
                #pragma unroll
                for (int mi = 0; mi < 8; ++mi) {
                    int m = m0 + mi;
                    int d = d0 + di;
                    int a = m * 65 + (d ^ mg);
                    if (w == 0) smem[a] = acc[di][mi];
                    else        smem[a] += acc[di][mi];
                }
        }
    }
    __syncthreads();

    // commit 4096-float partial, coalesced (no atomics)
    float* pb = part + (size_t)b * 4096;
    #pragma unroll
    for (int i = 0; i < 16; ++i) {
        int e = tid + (i << 8);
        int m = e >> 6, d = e & 63;
        pb[e] = smem[m * 65 + (d ^ ((m >> 3) & 7))];
    }

    // ksum partial: cross-wave reduce through LDS, then one coalesced store
    __syncthreads();
    if (mg == 0) {
        #pragma unroll
        for (int di = 0; di < 8; ++di) smem[(wave << 6) + d0 + di] = ks[di];
    }
    __syncthreads();
    if (tid < 64)
        kspart[(b << 6) + tid] =
            smem[tid] + smem[64 + tid] + smem[128 + tid] + smem[192 + tid];
}

// sum 32 per-chunk partials -> final kv (in ws) and ksum (in ws)
__global__ void reduce_kernel(const float* __restrict__ part,
                              const float* __restrict__ kspart,
                              float* __restrict__ kvf, float* __restrict__ ksf) {
    int i = blockIdx.x * 256 + threadIdx.x;
    if (i < NHH * 4096) {
        int nh = i >> 12, e = i & 4095;
        const float* p = part + ((size_t)nh << 17) + e;   // nh*32*4096
        float s = 0.0f;
        #pragma unroll
        for (int c = 0; c < 32; ++c) s += p[(size_t)c << 12];
        kvf[i] = s;
    } else if (i < NHH * 4096 + NHH * 64) {
        int j = i - NHH * 4096;
        int nh = j >> 6, d = j & 63;
        const float* p = kspart + ((size_t)(nh << 5) << 6) + d;  // (nh*32+c)*64 + d
        float s = 0.0f;
        #pragma unroll
        for (int c = 0; c < 32; ++c) s += p[c << 6];
        ksf[j] = s;
    }
}

// Phase 2: out[nh][l][m] = z(l) * sum_d feat(q[l][d]) * kv[m][d]
// grid = NHH * (LL/128) blocks, 256 threads, Ltile=128, 4l x 8m per-thread tile.
__global__ __launch_bounds__(256, 2) void phase2_kernel(
        const float* __restrict__ qg, const float* __restrict__ kvf,
        const float* __restrict__ ksf, float* __restrict__ out) {
    __shared__ float s_kv[64 * 68];
    __shared__ float s_qf[128 * 68];
    __shared__ float s_z[128];

    int b = blockIdx.x;
    int nh = b >> 7;               // /128 tiles
    int lt = (b & 127) << 7;       // tile base l
    int n = nh >> 3, h = nh & 7;
    int tid = threadIdx.x;

    // load kv[nh][m][d] into LDS (pitch 68)
    const float* kvg = kvf + (size_t)nh * 4096;
    #pragma unroll
    for (int kk = 0; kk < 4; ++kk) {
        int e4 = tid + (kk << 8);               // float4 index, 0..1023
        int m = e4 >> 4;
        int dcol = (e4 & 15) << 2;
        float4 x = *(const float4*)(kvg + ((size_t)e4 << 2));
        *(float4*)&s_kv[m * 68 + dcol] = x;
    }

    int dq = (tid & 15) << 2;
    float4 ks4 = *(const float4*)(ksf + nh * 64 + dq);

    // load q tile, apply feature map, compute z via 16-lane reduction
    const float* qb = qg + (((size_t)n * LL + lt) * HH + h) * DD;
    #pragma unroll
    for (int p = 0; p < 8; ++p) {
        int r = (p << 4) + (tid >> 4);
        float4 x = *(const float4*)(qb + (size_t)r * (HH * DD) + dq);
        float4 f;
        f.x = feat(x.x); f.y = feat(x.y); f.z = feat(x.z); f.w = feat(x.w);
        *(float4*)&s_qf[r * 68 + dq] = f;
        float pz = f.x * ks4.x + f.y * ks4.y + f.z * ks4.z + f.w * ks4.w;
        pz += __shfl_xor(pz, 1);
        pz += __shfl_xor(pz, 2);
        pz += __shfl_xor(pz, 4);
        pz += __shfl_xor(pz, 8);
        if ((tid & 15) == 0) s_z[r] = 1.0f / (pz + EPSF);
    }
    __syncthreads();

    int t = tid & 31;              // l-lane (strided l: l = t + 32*i)
    int m0 = (tid >> 5) << 3;      // 8 m's per thread

    float acc[4][8];
    #pragma unroll
    for (int i2 = 0; i2 < 4; ++i2)
        #pragma unroll
        for (int j = 0; j < 8; ++j) acc[i2][j] = 0.0f;

    #pragma unroll
    for (int dB = 0; dB < 64; dB += 4) {
        float4 qv[4];
        #pragma unroll
        for (int i2 = 0; i2 < 4; ++i2)
            qv[i2] = *(float4*)&s_qf[(t + (i2 << 5)) * 68 + dB];
        #pragma unroll
        for (int j = 0; j < 8; ++j) {
            float4 kd = *(float4*)&s_kv[(m0 + j) * 68 + dB];
            #pragma unroll
            for (int i2 = 0; i2 < 4; ++i2) {
                acc[i2][j] = fmaf(qv[i2].x, kd.x, acc[i2][j]);
                acc[i2][j] = fmaf(qv[i2].y, kd.y, acc[i2][j]);
                acc[i2][j] = fmaf(qv[i2].z, kd.z, acc[i2][j]);
                acc[i2][j] = fmaf(qv[i2].w, kd.w, acc[i2][j]);
            }
        }
    }

    // epilogue: scale by z, store out[nh][l][m]
    float* ob = out + ((size_t)nh * LL + lt) * 64;
    #pragma unroll
    for (int i2 = 0; i2 < 4; ++i2) {
        int l = t + (i2 << 5);
        float z = s_z[l];
        float4 o0, o1;
        o0.x = acc[i2][0] * z; o0.y = acc[i2][1] * z;
        o0.z = acc[i2][2] * z; o0.w = acc[i2][3] * z;
        o1.x = acc[i2][4] * z; o1.y = acc[i2][5] * z;
        o1.z = acc[i2][6] * z; o1.w = acc[i2][7] * z;
        *(float4*)(ob + (size_t)l * 64 + m0) = o0;
        *(float4*)(ob + (size_t)l * 64 + m0 + 4) = o1;
    }
}

extern "C" void kernel_launch(void* const* d_in, const int* in_sizes, int n_in,
                              void* d_out, int out_size, void* d_ws, size_t ws_size,
                              hipStream_t stream) {
    const float* qg = (const float*)d_in[0];
    const float* kg = (const float*)d_in[1];
    const float* vg = (const float*)d_in[2];
    float* outp = (float*)d_out;

    // scratch partials live in d_out (phase2 fully overwrites it afterwards):
    //   part:   [1024][4096] floats = 16.8 MB
    //   kspart: [1024][64]   floats = 0.26 MB
    float* part   = outp;
    float* kspart = outp + (size_t)NHH * SPLIT * 4096;

    // final kv / ksum live in ws (532 KB; proven available)
    float* kvf = (float*)d_ws;                  // [32][64][64]
    float* ksf = kvf + NHH * 4096;              // [32][64]

    hipLaunchKernelGGL(phase1_kernel, dim3(NHH * SPLIT), dim3(256), 0, stream,
                       kg, vg, part, kspart);
    hipLaunchKernelGGL(reduce_kernel, dim3(520), dim3(256), 0, stream,
                       part, kspart, kvf, ksf);
    hipLaunchKernelGGL(phase2_kernel, dim3(NHH * (LL / 128)), dim3(256), 0, stream,
                       qg, kvf, ksf, outp);
}